// Round 4
// baseline (1340.282 us; speedup 1.0000x reference)
//
#include <hip/hip_runtime.h>
#include <stdint.h>

// CA model constants (match reference)
#define BB 8
#define CC 16
#define HH_ 128
#define WW 128
#define HIDN 128
#define HWSZ (HH_ * WW)          // 16384
#define NPIX (BB * HWSZ)         // 131072
#define NSTEPS 16

// ---------------------------------------------------------------------------
// Threefry-2x32, 20 rounds — exact JAX implementation (partitionable mode).
// ---------------------------------------------------------------------------
__host__ __device__ inline void threefry2x32(uint32_t k0, uint32_t k1,
                                             uint32_t x0, uint32_t x1,
                                             uint32_t* o0, uint32_t* o1) {
  uint32_t ks[3] = {k0, k1, k0 ^ k1 ^ 0x1BD11BDAu};
  const uint32_t rots[2][4] = {{13u, 15u, 26u, 6u}, {17u, 29u, 16u, 24u}};
  x0 += ks[0];
  x1 += ks[1];
#pragma unroll
  for (int g = 0; g < 5; ++g) {
    const uint32_t* r = rots[g & 1];
#pragma unroll
    for (int i = 0; i < 4; ++i) {
      x0 += x1;
      x1 = (x1 << r[i]) | (x1 >> (32u - r[i]));
      x1 ^= x0;
    }
    x0 += ks[(g + 1) % 3];
    x1 += ks[(g + 2) % 3] + (uint32_t)(g + 1);
  }
  *o0 = x0;
  *o1 = x1;
}

__device__ __forceinline__ float jax_mask_bit(uint32_t key0, uint32_t key1, int g) {
  uint32_t t0, t1;
  threefry2x32(key0, key1, 0u, (uint32_t)g, &t0, &t1);
  uint32_t bits = t0 ^ t1;
  float u = __uint_as_float((bits >> 9) | 0x3f800000u) - 1.0f;
  return (u < 0.5f) ? 1.0f : 0.0f;
}

// ---------------------------------------------------------------------------
// Kernel A: sobel perception + MLP + mask -> writes "new" state to nxt.
// 128 threads/block, 2 px/thread (vertically adjacent rows) -> 256 px/block.
// Weights in LDS, broadcast ds_read_b128; 134 FMA per 17 LDS ops per hh.
// ---------------------------------------------------------------------------
__global__ __launch_bounds__(128, 1) void ca_step_mlp(
    const float* __restrict__ cur, const float* __restrict__ w1,
    const float* __restrict__ b1, const float* __restrict__ w2,
    const float* __restrict__ b2, float* __restrict__ nxt,
    uint32_t key0, uint32_t key1) {
  __shared__ float lw1[HIDN * 48];   // 24576 B, row-major [hh][48]
  __shared__ float lb1[HIDN];        // 512 B
  __shared__ float lw2t[HIDN * CC];  // 8192 B, [hh][o]

  // --- staging (one-time) ---
  {
    const float4* gw1 = (const float4*)w1;
    float4* s1 = (float4*)lw1;
#pragma unroll
    for (int i = threadIdx.x; i < HIDN * 12; i += 128) s1[i] = gw1[i];  // coalesced
    lb1[threadIdx.x] = b1[threadIdx.x];
    for (int i = threadIdx.x; i < HIDN * CC; i += 128) {
      int hh = i >> 4, o = i & 15;           // consecutive lanes -> consecutive LDS
      lw2t[i] = w2[o * HIDN + hh];           // conflict-free writes; reads hit L2
    }
  }
  __syncthreads();

  const int g0 = blockIdx.x * 256 + threadIdx.x;  // px0; px1 = g0 + 128
  const int b = g0 >> 14;
  const int hw0 = g0 & (HWSZ - 1);
  const int r = hw0 >> 7;  // even, 0..126 (blocks cover 2 full rows)
  const int w = hw0 & (WW - 1);

  const bool hu = r > 0, hd = r < HH_ - 2, wl = w > 0, wr = w < WW - 1;
  const int du = hu ? -WW : 0;       // row r-1
  const int dd = hd ? 2 * WW : 0;    // row r+2
  const int dl = wl ? -1 : 0;
  const int dr = wr ? 1 : 0;

  const float* xb = cur + (size_t)b * CC * HWSZ + hw0;

  // perception for both pixels: p{0,1} = [ident(16) | sx(16) | sy(16)]
  float p0[48], p1[48];
#pragma unroll
  for (int c = 0; c < CC; ++c) {
    const float* xc = xb + c * HWSZ;
    // 4 stencil rows (r-1, r, r+1, r+2) x 3 cols = 12 loads for 2 pixels
    float A0l = xc[du + dl], A0m = xc[du], A0r = xc[du + dr];
    if (!hu) { A0l = 0.f; A0m = 0.f; A0r = 0.f; }
    else { if (!wl) A0l = 0.f; if (!wr) A0r = 0.f; }
    float A1l = xc[dl], A1m = xc[0], A1r = xc[dr];
    if (!wl) A1l = 0.f;
    if (!wr) A1r = 0.f;
    float A2l = xc[WW + dl], A2m = xc[WW], A2r = xc[WW + dr];  // row r+1 always valid
    if (!wl) A2l = 0.f;
    if (!wr) A2r = 0.f;
    float A3l = xc[dd + dl], A3m = xc[dd], A3r = xc[dd + dr];
    if (!hd) { A3l = 0.f; A3m = 0.f; A3r = 0.f; }
    else { if (!wl) A3l = 0.f; if (!wr) A3r = 0.f; }

    p0[c] = A1m;
    p0[16 + c] = (A0l - A0r + 2.f * (A1l - A1r) + A2l - A2r) * 0.125f;
    p0[32 + c] = (A0l + 2.f * A0m + A0r - A2l - 2.f * A2m - A2r) * 0.125f;
    p1[c] = A2m;
    p1[16 + c] = (A1l - A1r + 2.f * (A2l - A2r) + A3l - A3r) * 0.125f;
    p1[32 + c] = (A1l + 2.f * A1m + A1r - A3l - 2.f * A3m - A3r) * 0.125f;
  }

  float diff0[CC], diff1[CC];
#pragma unroll
  for (int o = 0; o < CC; ++o) {
    float bo = b2[o];  // uniform -> s_load
    diff0[o] = bo;
    diff1[o] = bo;
  }

  for (int hh = 0; hh < HIDN; ++hh) {
    const float4* wrow = (const float4*)(lw1 + hh * 48);
    const float bb = lb1[hh];
    float a0 = bb, a1 = 0.f, a2 = 0.f, a3 = 0.f;  // px0
    float c0 = bb, c1 = 0.f, c2 = 0.f, c3 = 0.f;  // px1
#pragma unroll
    for (int q = 0; q < 12; ++q) {
      float4 wv = wrow[q];
      const int k = q * 4;
      float* ap;
      float* cp;
      // rotate accumulators to keep dep chains short
      switch (q & 3) {
        case 0: ap = &a0; cp = &c0; break;
        case 1: ap = &a1; cp = &c1; break;
        case 2: ap = &a2; cp = &c2; break;
        default: ap = &a3; cp = &c3; break;
      }
      float av = *ap, cv = *cp;
      av = fmaf(wv.x, p0[k + 0], av);
      av = fmaf(wv.y, p0[k + 1], av);
      av = fmaf(wv.z, p0[k + 2], av);
      av = fmaf(wv.w, p0[k + 3], av);
      cv = fmaf(wv.x, p1[k + 0], cv);
      cv = fmaf(wv.y, p1[k + 1], cv);
      cv = fmaf(wv.z, p1[k + 2], cv);
      cv = fmaf(wv.w, p1[k + 3], cv);
      *ap = av;
      *cp = cv;
    }
    float h0 = fmaxf((a0 + a1) + (a2 + a3), 0.f);
    float h1 = fmaxf((c0 + c1) + (c2 + c3), 0.f);

    const float4* w2r = (const float4*)(lw2t + hh * CC);
#pragma unroll
    for (int o4 = 0; o4 < 4; ++o4) {
      float4 wv = w2r[o4];
      diff0[o4 * 4 + 0] = fmaf(wv.x, h0, diff0[o4 * 4 + 0]);
      diff0[o4 * 4 + 1] = fmaf(wv.y, h0, diff0[o4 * 4 + 1]);
      diff0[o4 * 4 + 2] = fmaf(wv.z, h0, diff0[o4 * 4 + 2]);
      diff0[o4 * 4 + 3] = fmaf(wv.w, h0, diff0[o4 * 4 + 3]);
      diff1[o4 * 4 + 0] = fmaf(wv.x, h1, diff1[o4 * 4 + 0]);
      diff1[o4 * 4 + 1] = fmaf(wv.y, h1, diff1[o4 * 4 + 1]);
      diff1[o4 * 4 + 2] = fmaf(wv.z, h1, diff1[o4 * 4 + 2]);
      diff1[o4 * 4 + 3] = fmaf(wv.w, h1, diff1[o4 * 4 + 3]);
    }
  }

  const float m0 = jax_mask_bit(key0, key1, g0);
  const float m1 = jax_mask_bit(key0, key1, g0 + 128);

  float* nb = nxt + (size_t)b * CC * HWSZ + hw0;
#pragma unroll
  for (int c = 0; c < CC; ++c) {
    nb[c * HWSZ] = fmaf(diff0[c], m0, p0[c]);        // row r
    nb[c * HWSZ + WW] = fmaf(diff1[c], m1, p1[c]);   // row r+1
  }
}

// ---------------------------------------------------------------------------
// Kernel B: 3x3 max-pool on alpha (ch 3), alive gate, write next state
// ---------------------------------------------------------------------------
__global__ __launch_bounds__(256) void ca_step_alive(
    const float* __restrict__ nw, float* __restrict__ out) {
  const int g = blockIdx.x * 256 + threadIdx.x;
  const int b = g >> 14;
  const int hw = g & (HWSZ - 1);
  const int h = hw >> 7;
  const int w = hw & (WW - 1);
  const bool hu = h > 0, hd = h < HH_ - 1, wl = w > 0, wr = w < WW - 1;

  const float* ab = nw + ((size_t)b * CC + 3) * HWSZ + hw;
  float pooled = ab[0];
  if (hu) {
    pooled = fmaxf(pooled, ab[-WW]);
    if (wl) pooled = fmaxf(pooled, ab[-WW - 1]);
    if (wr) pooled = fmaxf(pooled, ab[-WW + 1]);
  }
  if (hd) {
    pooled = fmaxf(pooled, ab[WW]);
    if (wl) pooled = fmaxf(pooled, ab[WW - 1]);
    if (wr) pooled = fmaxf(pooled, ab[WW + 1]);
  }
  if (wl) pooled = fmaxf(pooled, ab[-1]);
  if (wr) pooled = fmaxf(pooled, ab[1]);

  const float alive = (pooled > 0.1f) ? 1.0f : 0.0f;

  const float* nb = nw + (size_t)b * CC * HWSZ + hw;
  float* ob = out + (size_t)b * CC * HWSZ + hw;
#pragma unroll
  for (int c = 0; c < CC; ++c) ob[c * HWSZ] = nb[c * HWSZ] * alive;
}

// ---------------------------------------------------------------------------
extern "C" void kernel_launch(void* const* d_in, const int* in_sizes, int n_in,
                              void* d_out, int out_size, void* d_ws,
                              size_t ws_size, hipStream_t stream) {
  const float* x = (const float*)d_in[0];
  const float* w1 = (const float*)d_in[1];
  const float* b1 = (const float*)d_in[2];
  const float* w2 = (const float*)d_in[3];
  const float* b2 = (const float*)d_in[4];
  // d_in[5] = n_steps (16) — fixed at compile time

  float* out = (float*)d_out;
  float* nbuf = (float*)d_ws;  // NPIX*CC*4 = 8 MB scratch

  // step keys from split(key(42), 16), partitionable threefry
  uint32_t k0s[NSTEPS], k1s[NSTEPS];
  for (int s = 0; s < NSTEPS; ++s)
    threefry2x32(0u, 42u, 0u, (uint32_t)s, &k0s[s], &k1s[s]);

  dim3 gridA(NPIX / 256), blockA(128);
  dim3 gridB(NPIX / 256), blockB(256);
  for (int s = 0; s < NSTEPS; ++s) {
    const float* src = (s == 0) ? x : out;
    ca_step_mlp<<<gridA, blockA, 0, stream>>>(src, w1, b1, w2, b2, nbuf,
                                              k0s[s], k1s[s]);
    ca_step_alive<<<gridB, blockB, 0, stream>>>(nbuf, out);
  }
}

// Round 5
// 993.433 us; speedup vs baseline: 1.3491x; 1.3491x over previous
//
#include <hip/hip_runtime.h>
#include <stdint.h>

// CA model constants (match reference)
#define BB 8
#define CC 16
#define HH_ 128
#define WW 128
#define HIDN 128
#define HWSZ (HH_ * WW)          // 16384
#define NPIX (BB * HWSZ)         // 131072
#define NSTEPS 16

// ---------------------------------------------------------------------------
// Threefry-2x32, 20 rounds — exact JAX implementation (partitionable mode).
// ---------------------------------------------------------------------------
__host__ __device__ inline void threefry2x32(uint32_t k0, uint32_t k1,
                                             uint32_t x0, uint32_t x1,
                                             uint32_t* o0, uint32_t* o1) {
  uint32_t ks[3] = {k0, k1, k0 ^ k1 ^ 0x1BD11BDAu};
  const uint32_t rots[2][4] = {{13u, 15u, 26u, 6u}, {17u, 29u, 16u, 24u}};
  x0 += ks[0];
  x1 += ks[1];
#pragma unroll
  for (int g = 0; g < 5; ++g) {
    const uint32_t* r = rots[g & 1];
#pragma unroll
    for (int i = 0; i < 4; ++i) {
      x0 += x1;
      x1 = (x1 << r[i]) | (x1 >> (32u - r[i]));
      x1 ^= x0;
    }
    x0 += ks[(g + 1) % 3];
    x1 += ks[(g + 2) % 3] + (uint32_t)(g + 1);
  }
  *o0 = x0;
  *o1 = x1;
}

__device__ __forceinline__ float jax_mask_bit(uint32_t key0, uint32_t key1, int g) {
  uint32_t t0, t1;
  threefry2x32(key0, key1, 0u, (uint32_t)g, &t0, &t1);
  uint32_t bits = t0 ^ t1;
  float u = __uint_as_float((bits >> 9) | 0x3f800000u) - 1.0f;
  return (u < 0.5f) ? 1.0f : 0.0f;
}

// ---------------------------------------------------------------------------
// Kernel A: sobel perception + MLP + mask -> writes "new" state to nxt.
// 1 px/thread, 256 thr/block, 2 blocks/CU (8 waves/CU = 2/SIMD).
// w1/b1/b2 via wave-uniform s_load (scalar pipe); PHASE BARRIERS every 16 hh
// keep all waves in the same 3 KB w1 window so the scalar cache stays hot.
// w2^T in LDS (4 broadcast ds_read_b128/hh: 147 cyc/CU < 256 VALU budget).
// ---------------------------------------------------------------------------
__global__ __launch_bounds__(256, 2) void ca_step_mlp(
    const float* __restrict__ cur, const float* __restrict__ w1,
    const float* __restrict__ b1, const float* __restrict__ w2,
    const float* __restrict__ b2, float* __restrict__ nxt,
    uint32_t key0, uint32_t key1) {
  __shared__ float lw2t[HIDN * CC];  // 8192 B, [hh][o]

  // conflict-free staging: consecutive lanes -> consecutive LDS addresses
  for (int i = threadIdx.x; i < HIDN * CC; i += 256) {
    int hh = i >> 4, o = i & 15;
    lw2t[i] = w2[o * HIDN + hh];
  }
  __syncthreads();

  const int g = blockIdx.x * 256 + threadIdx.x;  // 0..NPIX-1
  const int b = g >> 14;
  const int hw = g & (HWSZ - 1);
  const int h = hw >> 7;
  const int w = hw & (WW - 1);

  const bool hu = h > 0, hd = h < HH_ - 1, wl = w > 0, wr = w < WW - 1;
  const int du = hu ? -WW : 0;
  const int dd = hd ? WW : 0;
  const int dl = wl ? -1 : 0;
  const int dr = wr ? 1 : 0;

  const float* xb = cur + (size_t)b * CC * HWSZ + hw;

  // perception: [ident(16) | sobel_x(16) | sobel_y(16)]
  float p[48];
#pragma unroll
  for (int c = 0; c < CC; ++c) {
    const float* xc = xb + c * HWSZ;
    float n00 = xc[du + dl]; if (!(hu && wl)) n00 = 0.f;
    float n01 = xc[du];      if (!hu)         n01 = 0.f;
    float n02 = xc[du + dr]; if (!(hu && wr)) n02 = 0.f;
    float n10 = xc[dl];      if (!wl)         n10 = 0.f;
    float n11 = xc[0];
    float n12 = xc[dr];      if (!wr)         n12 = 0.f;
    float n20 = xc[dd + dl]; if (!(hd && wl)) n20 = 0.f;
    float n21 = xc[dd];      if (!hd)         n21 = 0.f;
    float n22 = xc[dd + dr]; if (!(hd && wr)) n22 = 0.f;
    p[c] = n11;
    p[16 + c] = (n00 - n02 + 2.f * (n10 - n12) + n20 - n22) * 0.125f;
    p[32 + c] = (n00 + 2.f * n01 + n02 - n20 - 2.f * n21 - n22) * 0.125f;
  }

  float diff[CC];
#pragma unroll
  for (int o = 0; o < CC; ++o) diff[o] = b2[o];  // uniform -> s_load

  // hh loop in 8 phases of 16; barrier keeps waves' scalar-cache window shared
  for (int ph = 0; ph < 8; ++ph) {
    __syncthreads();
#pragma unroll
    for (int j = 0; j < 16; ++j) {
      const int hh = ph * 16 + j;  // wave-uniform -> s_load_dwordx4
      const float4* wrow = (const float4*)(w1 + hh * 48);
      float a0 = b1[hh], a1 = 0.f, a2 = 0.f, a3 = 0.f;
#pragma unroll
      for (int q = 0; q < 3; ++q) {
        float4 w0 = wrow[q * 4 + 0];
        float4 w1v = wrow[q * 4 + 1];
        float4 w2v = wrow[q * 4 + 2];
        float4 w3 = wrow[q * 4 + 3];
        const int base = q * 16;
        a0 = fmaf(w0.x, p[base + 0], a0);
        a0 = fmaf(w0.y, p[base + 1], a0);
        a0 = fmaf(w0.z, p[base + 2], a0);
        a0 = fmaf(w0.w, p[base + 3], a0);
        a1 = fmaf(w1v.x, p[base + 4], a1);
        a1 = fmaf(w1v.y, p[base + 5], a1);
        a1 = fmaf(w1v.z, p[base + 6], a1);
        a1 = fmaf(w1v.w, p[base + 7], a1);
        a2 = fmaf(w2v.x, p[base + 8], a2);
        a2 = fmaf(w2v.y, p[base + 9], a2);
        a2 = fmaf(w2v.z, p[base + 10], a2);
        a2 = fmaf(w2v.w, p[base + 11], a2);
        a3 = fmaf(w3.x, p[base + 12], a3);
        a3 = fmaf(w3.y, p[base + 13], a3);
        a3 = fmaf(w3.z, p[base + 14], a3);
        a3 = fmaf(w3.w, p[base + 15], a3);
      }
      float acc = (a0 + a1) + (a2 + a3);
      acc = fmaxf(acc, 0.f);
      const float4* w2r = (const float4*)(lw2t + hh * CC);
#pragma unroll
      for (int o4 = 0; o4 < 4; ++o4) {
        float4 wv = w2r[o4];
        diff[o4 * 4 + 0] = fmaf(wv.x, acc, diff[o4 * 4 + 0]);
        diff[o4 * 4 + 1] = fmaf(wv.y, acc, diff[o4 * 4 + 1]);
        diff[o4 * 4 + 2] = fmaf(wv.z, acc, diff[o4 * 4 + 2]);
        diff[o4 * 4 + 3] = fmaf(wv.w, acc, diff[o4 * 4 + 3]);
      }
    }
  }

  const float m = jax_mask_bit(key0, key1, g);

  float* nb = nxt + (size_t)b * CC * HWSZ + hw;
#pragma unroll
  for (int c = 0; c < CC; ++c) {
    nb[c * HWSZ] = fmaf(diff[c], m, p[c]);  // exact: m in {0,1}
  }
}

// ---------------------------------------------------------------------------
// Kernel B: 3x3 max-pool on alpha (ch 3), alive gate, write next state
// ---------------------------------------------------------------------------
__global__ __launch_bounds__(256) void ca_step_alive(
    const float* __restrict__ nw, float* __restrict__ out) {
  const int g = blockIdx.x * 256 + threadIdx.x;
  const int b = g >> 14;
  const int hw = g & (HWSZ - 1);
  const int h = hw >> 7;
  const int w = hw & (WW - 1);
  const bool hu = h > 0, hd = h < HH_ - 1, wl = w > 0, wr = w < WW - 1;

  const float* ab = nw + ((size_t)b * CC + 3) * HWSZ + hw;
  float pooled = ab[0];
  if (hu) {
    pooled = fmaxf(pooled, ab[-WW]);
    if (wl) pooled = fmaxf(pooled, ab[-WW - 1]);
    if (wr) pooled = fmaxf(pooled, ab[-WW + 1]);
  }
  if (hd) {
    pooled = fmaxf(pooled, ab[WW]);
    if (wl) pooled = fmaxf(pooled, ab[WW - 1]);
    if (wr) pooled = fmaxf(pooled, ab[WW + 1]);
  }
  if (wl) pooled = fmaxf(pooled, ab[-1]);
  if (wr) pooled = fmaxf(pooled, ab[1]);

  const float alive = (pooled > 0.1f) ? 1.0f : 0.0f;

  const float* nb = nw + (size_t)b * CC * HWSZ + hw;
  float* ob = out + (size_t)b * CC * HWSZ + hw;
#pragma unroll
  for (int c = 0; c < CC; ++c) ob[c * HWSZ] = nb[c * HWSZ] * alive;
}

// ---------------------------------------------------------------------------
extern "C" void kernel_launch(void* const* d_in, const int* in_sizes, int n_in,
                              void* d_out, int out_size, void* d_ws,
                              size_t ws_size, hipStream_t stream) {
  const float* x = (const float*)d_in[0];
  const float* w1 = (const float*)d_in[1];
  const float* b1 = (const float*)d_in[2];
  const float* w2 = (const float*)d_in[3];
  const float* b2 = (const float*)d_in[4];
  // d_in[5] = n_steps (16) — fixed at compile time

  float* out = (float*)d_out;
  float* nbuf = (float*)d_ws;  // NPIX*CC*4 = 8 MB scratch

  // step keys from split(key(42), 16), partitionable threefry
  uint32_t k0s[NSTEPS], k1s[NSTEPS];
  for (int s = 0; s < NSTEPS; ++s)
    threefry2x32(0u, 42u, 0u, (uint32_t)s, &k0s[s], &k1s[s]);

  dim3 grid(NPIX / 256), block(256);
  for (int s = 0; s < NSTEPS; ++s) {
    const float* src = (s == 0) ? x : out;
    ca_step_mlp<<<grid, block, 0, stream>>>(src, w1, b1, w2, b2, nbuf,
                                            k0s[s], k1s[s]);
    ca_step_alive<<<grid, block, 0, stream>>>(nbuf, out);
  }
}

// Round 6
// 893.558 us; speedup vs baseline: 1.4999x; 1.1118x over previous
//
#include <hip/hip_runtime.h>
#include <stdint.h>

// CA model constants (match reference)
#define BB 8
#define CC 16
#define HH_ 128
#define WW 128
#define HIDN 128
#define HWSZ (HH_ * WW)          // 16384
#define NPIX (BB * HWSZ)         // 131072
#define NSTEPS 16

// ---------------------------------------------------------------------------
// Threefry-2x32, 20 rounds — exact JAX implementation (partitionable mode).
// ---------------------------------------------------------------------------
__host__ __device__ inline void threefry2x32(uint32_t k0, uint32_t k1,
                                             uint32_t x0, uint32_t x1,
                                             uint32_t* o0, uint32_t* o1) {
  uint32_t ks[3] = {k0, k1, k0 ^ k1 ^ 0x1BD11BDAu};
  const uint32_t rots[2][4] = {{13u, 15u, 26u, 6u}, {17u, 29u, 16u, 24u}};
  x0 += ks[0];
  x1 += ks[1];
#pragma unroll
  for (int g = 0; g < 5; ++g) {
    const uint32_t* r = rots[g & 1];
#pragma unroll
    for (int i = 0; i < 4; ++i) {
      x0 += x1;
      x1 = (x1 << r[i]) | (x1 >> (32u - r[i]));
      x1 ^= x0;
    }
    x0 += ks[(g + 1) % 3];
    x1 += ks[(g + 2) % 3] + (uint32_t)(g + 1);
  }
  *o0 = x0;
  *o1 = x1;
}

__device__ __forceinline__ float jax_mask_bit(uint32_t key0, uint32_t key1, int g) {
  uint32_t t0, t1;
  threefry2x32(key0, key1, 0u, (uint32_t)g, &t0, &t1);
  uint32_t bits = t0 ^ t1;
  float u = __uint_as_float((bits >> 9) | 0x3f800000u) - 1.0f;
  return (u < 0.5f) ? 1.0f : 0.0f;
}

#define FMA4(acc, wv, pp, k)          \
  acc = fmaf(wv.x, pp[(k) + 0], acc); \
  acc = fmaf(wv.y, pp[(k) + 1], acc); \
  acc = fmaf(wv.z, pp[(k) + 2], acc); \
  acc = fmaf(wv.w, pp[(k) + 3], acc);

// ---------------------------------------------------------------------------
// Kernel A: sobel perception + MLP + mask -> writes "new" state to nxt.
// 1 px/thread, 256 thr/block, 2 blocks/CU (8 waves/CU), NO in-loop barriers.
// w1 cols[16:48) in LDS, ping-pong double-buffered one row ahead (8 broadcast
// ds_read_b128/hh). w1 cols[0:16), b1, w2, b2 on the scalar pipe (hot ~16KB
// K$ set; w2 read as contiguous 64B rows per 16-hh chunk -> s_load_dwordx16).
// ---------------------------------------------------------------------------
__global__ __launch_bounds__(256, 2) void ca_step_mlp(
    const float* __restrict__ cur, const float* __restrict__ w1,
    const float* __restrict__ b1, const float* __restrict__ w2,
    const float* __restrict__ b2, float* __restrict__ nxt,
    uint32_t key0, uint32_t key1) {
  __shared__ float lw1hi[HIDN * 32];  // 16384 B: w1[hh][16..48)

  for (int i = threadIdx.x; i < HIDN * 8; i += 256) {
    int hh = i >> 3, q = i & 7;
    ((float4*)lw1hi)[i] = ((const float4*)(w1 + hh * 48 + 16))[q];
  }
  __syncthreads();

  const int g = blockIdx.x * 256 + threadIdx.x;  // 0..NPIX-1
  const int b = g >> 14;
  const int hw = g & (HWSZ - 1);
  const int h = hw >> 7;
  const int w = hw & (WW - 1);

  const bool hu = h > 0, hd = h < HH_ - 1, wl = w > 0, wr = w < WW - 1;
  const int du = hu ? -WW : 0;
  const int dd = hd ? WW : 0;
  const int dl = wl ? -1 : 0;
  const int dr = wr ? 1 : 0;

  const float* xb = cur + (size_t)b * CC * HWSZ + hw;

  // perception: [ident(16) | sobel_x(16) | sobel_y(16)]
  float p[48];
#pragma unroll
  for (int c = 0; c < CC; ++c) {
    const float* xc = xb + c * HWSZ;
    float n00 = xc[du + dl]; if (!(hu && wl)) n00 = 0.f;
    float n01 = xc[du];      if (!hu)         n01 = 0.f;
    float n02 = xc[du + dr]; if (!(hu && wr)) n02 = 0.f;
    float n10 = xc[dl];      if (!wl)         n10 = 0.f;
    float n11 = xc[0];
    float n12 = xc[dr];      if (!wr)         n12 = 0.f;
    float n20 = xc[dd + dl]; if (!(hd && wl)) n20 = 0.f;
    float n21 = xc[dd];      if (!hd)         n21 = 0.f;
    float n22 = xc[dd + dr]; if (!(hd && wr)) n22 = 0.f;
    p[c] = n11;
    p[16 + c] = (n00 - n02 + 2.f * (n10 - n12) + n20 - n22) * 0.125f;
    p[32 + c] = (n00 + 2.f * n01 + n02 - n20 - 2.f * n21 - n22) * 0.125f;
  }

  float diff[CC];
#pragma unroll
  for (int o = 0; o < CC; ++o) diff[o] = b2[o];  // uniform -> s_load

  const float4* lw = (const float4*)lw1hi;  // [hh*8 + q]
  float4 bufA[8], bufB[8];
#pragma unroll
  for (int q = 0; q < 8; ++q) bufA[q] = lw[q];  // preload row 0

  float hacc[16];

  for (int chunk = 0; chunk < 8; ++chunk) {
#pragma unroll
    for (int j = 0; j < 16; ++j) {
      const int hh = chunk * 16 + j;
      const int hnx = (hh + 1) & 127;
      // ping-pong: even j computes from bufA, prefetches row hh+1 into bufB
      float4* pb = (j & 1) ? bufA : bufB;
      const float4* cb = (j & 1) ? bufB : bufA;
#pragma unroll
      for (int q = 0; q < 8; ++q) pb[q] = lw[hnx * 8 + q];  // ds_read_b128 x8

      const float4* wlo = (const float4*)(w1 + hh * 48);  // uniform -> s_load
      float4 l0 = wlo[0], l1 = wlo[1], l2 = wlo[2], l3 = wlo[3];
      float a0 = b1[hh], a1 = 0.f, a2 = 0.f, a3 = 0.f;
      FMA4(a0, l0, p, 0)
      FMA4(a1, l1, p, 4)
      FMA4(a2, l2, p, 8)
      FMA4(a3, l3, p, 12)
      FMA4(a0, cb[0], p, 16)
      FMA4(a1, cb[1], p, 20)
      FMA4(a2, cb[2], p, 24)
      FMA4(a3, cb[3], p, 28)
      FMA4(a0, cb[4], p, 32)
      FMA4(a1, cb[5], p, 36)
      FMA4(a2, cb[6], p, 40)
      FMA4(a3, cb[7], p, 44)
      hacc[j] = fmaxf((a0 + a1) + (a2 + a3), 0.f);
    }
    // layer 2: w2 native layout, contiguous 64B rows -> s_load_dwordx16
#pragma unroll
    for (int o = 0; o < CC; ++o) {
      const float4* w2r = (const float4*)(w2 + o * HIDN + chunk * 16);
      float4 u0 = w2r[0], u1 = w2r[1], u2 = w2r[2], u3 = w2r[3];
      float d = diff[o];
      d = fmaf(u0.x, hacc[0], d);
      d = fmaf(u0.y, hacc[1], d);
      d = fmaf(u0.z, hacc[2], d);
      d = fmaf(u0.w, hacc[3], d);
      d = fmaf(u1.x, hacc[4], d);
      d = fmaf(u1.y, hacc[5], d);
      d = fmaf(u1.z, hacc[6], d);
      d = fmaf(u1.w, hacc[7], d);
      d = fmaf(u2.x, hacc[8], d);
      d = fmaf(u2.y, hacc[9], d);
      d = fmaf(u2.z, hacc[10], d);
      d = fmaf(u2.w, hacc[11], d);
      d = fmaf(u3.x, hacc[12], d);
      d = fmaf(u3.y, hacc[13], d);
      d = fmaf(u3.z, hacc[14], d);
      d = fmaf(u3.w, hacc[15], d);
      diff[o] = d;
    }
  }

  const float m = jax_mask_bit(key0, key1, g);

  float* nb = nxt + (size_t)b * CC * HWSZ + hw;
#pragma unroll
  for (int c = 0; c < CC; ++c) {
    nb[c * HWSZ] = fmaf(diff[c], m, p[c]);  // exact: m in {0,1}
  }
}

// ---------------------------------------------------------------------------
// Kernel B: 3x3 max-pool on alpha (ch 3), alive gate, write next state
// ---------------------------------------------------------------------------
__global__ __launch_bounds__(256) void ca_step_alive(
    const float* __restrict__ nw, float* __restrict__ out) {
  const int g = blockIdx.x * 256 + threadIdx.x;
  const int b = g >> 14;
  const int hw = g & (HWSZ - 1);
  const int h = hw >> 7;
  const int w = hw & (WW - 1);
  const bool hu = h > 0, hd = h < HH_ - 1, wl = w > 0, wr = w < WW - 1;

  const float* ab = nw + ((size_t)b * CC + 3) * HWSZ + hw;
  float pooled = ab[0];
  if (hu) {
    pooled = fmaxf(pooled, ab[-WW]);
    if (wl) pooled = fmaxf(pooled, ab[-WW - 1]);
    if (wr) pooled = fmaxf(pooled, ab[-WW + 1]);
  }
  if (hd) {
    pooled = fmaxf(pooled, ab[WW]);
    if (wl) pooled = fmaxf(pooled, ab[WW - 1]);
    if (wr) pooled = fmaxf(pooled, ab[WW + 1]);
  }
  if (wl) pooled = fmaxf(pooled, ab[-1]);
  if (wr) pooled = fmaxf(pooled, ab[1]);

  const float alive = (pooled > 0.1f) ? 1.0f : 0.0f;

  const float* nb = nw + (size_t)b * CC * HWSZ + hw;
  float* ob = out + (size_t)b * CC * HWSZ + hw;
#pragma unroll
  for (int c = 0; c < CC; ++c) ob[c * HWSZ] = nb[c * HWSZ] * alive;
}

// ---------------------------------------------------------------------------
extern "C" void kernel_launch(void* const* d_in, const int* in_sizes, int n_in,
                              void* d_out, int out_size, void* d_ws,
                              size_t ws_size, hipStream_t stream) {
  const float* x = (const float*)d_in[0];
  const float* w1 = (const float*)d_in[1];
  const float* b1 = (const float*)d_in[2];
  const float* w2 = (const float*)d_in[3];
  const float* b2 = (const float*)d_in[4];
  // d_in[5] = n_steps (16) — fixed at compile time

  float* out = (float*)d_out;
  float* nbuf = (float*)d_ws;  // NPIX*CC*4 = 8 MB scratch

  // step keys from split(key(42), 16), partitionable threefry
  uint32_t k0s[NSTEPS], k1s[NSTEPS];
  for (int s = 0; s < NSTEPS; ++s)
    threefry2x32(0u, 42u, 0u, (uint32_t)s, &k0s[s], &k1s[s]);

  dim3 grid(NPIX / 256), block(256);
  for (int s = 0; s < NSTEPS; ++s) {
    const float* src = (s == 0) ? x : out;
    ca_step_mlp<<<grid, block, 0, stream>>>(src, w1, b1, w2, b2, nbuf,
                                            k0s[s], k1s[s]);
    ca_step_alive<<<grid, block, 0, stream>>>(nbuf, out);
  }
}